// Round 11
// baseline (465.886 us; speedup 1.0000x reference)
//
#include <hip/hip_runtime.h>

// ImplicitNet fused MLP — R11: R10 with b single-buffered -> 3 blocks/CU.
// 256 threads (4 waves), 64 pts/block, wave owns 64 feats, IN-PLACE 32KB LDS.
// Register diet: drop b_nxt (-32 regs) -> ~145 unified <= 170 cap of
// __launch_bounds__(256,3) -> 3 blocks/CU = 3 waves/SIMD from DIFFERENT blocks
// (phase diversity). a-dbuf kept: L2 latency (200-600cyc) is the long pole;
// b's ~150cyc/K-step LDS exposure is what the 3rd wave fills.
// Kept from R10: prep layout, lgkm-only barriers, bias-in-C-init, in-place
// epilogue, packed softplus, W4 1/sqrt2 fold, cross-layer ks=0 prefetch, setprio.
//
// d_ws: bf16 weights, fragment-major 16x16x32: chunk(ntile,ktile,lane) holds
// W[ntile*16+(lane&15)][ktile*32+(lane>>4)*8+j]. Padding: L0 K 51->64,
// L3 N 253->256, L8 N 257->272. ws >= 1,089,536 B.

typedef __attribute__((ext_vector_type(8))) short bf16x8;
typedef __attribute__((ext_vector_type(4))) float f32x4;
typedef __attribute__((ext_vector_type(2))) float f32x2;

#define PPTS 50000

__device__ __forceinline__ short f2bf(float f) {
    union { float f; unsigned u; } v; v.f = f;
    unsigned r = v.u + 0x7fffu + ((v.u >> 16) & 1u);   // RTNE (finite inputs)
    return (short)(r >> 16);
}

__device__ __forceinline__ unsigned cvt_pk_bf16(float lo, float hi) {
    unsigned r;
    asm("v_cvt_pk_bf16_f32 %0, %1, %2" : "=v"(r) : "v"(lo), "v"(hi));
    return r;
}

// lgkm-only barrier: LDS ordering without draining the global (weight) queue.
__device__ __forceinline__ void bar_lgkm() {
    asm volatile("s_waitcnt lgkmcnt(0)" ::: "memory");
    __builtin_amdgcn_s_barrier();
    __builtin_amdgcn_sched_barrier(0);
}

// softplus(100x)/100 = max(x,0) + e*(A+Be+Ce^2), e=exp(-100|x|); |err|<=2.5e-5
__device__ __forceinline__ f32x2 sp100_pair(f32x2 y) {
    const f32x2 A2 = {6.9314718e-3f, 6.9314718e-3f};
    const f32x2 B2 = {-3.11522e-3f, -3.11522e-3f};
    const f32x2 C2 = {9.8829e-4f,  9.8829e-4f};
    const f32x2 K2 = {-144.26950408889634f, -144.26950408889634f};
    const f32x2 Z2 = {0.0f, 0.0f};
    f32x2 m = __builtin_elementwise_abs(y) * K2;
    f32x2 e = {__builtin_amdgcn_exp2f(m.x), __builtin_amdgcn_exp2f(m.y)};
    f32x2 t = __builtin_elementwise_fma(C2, e, B2);
    t = __builtin_elementwise_fma(t, e, A2);
    return __builtin_elementwise_fma(e, t, __builtin_elementwise_max(y, Z2));
}
__device__ __forceinline__ void sp100_4(f32x4& v) {
    f32x2 y0 = {v[0], v[1]}, y1 = {v[2], v[3]};
    f32x2 r0 = sp100_pair(y0), r1 = sp100_pair(y1);
    v[0] = r0.x; v[1] = r0.y; v[2] = r1.x; v[3] = r1.y;
}

// LDS tile [64 rows][256 cols] bf16, row stride 512B.
// byte ^= ((row&7) ^ 5*bit3(row)) << 4 — bijective, keeps 8/16B alignment.
__device__ __forceinline__ int xswz(int row) {
    return (((row & 7) ^ (5 * ((row >> 3) & 1))) << 4);
}
__device__ __forceinline__ short* xaddr(short* base, int row, int col) {
    int off = ((row << 9) + (col << 1)) ^ xswz(row);
    return (short*)((char*)base + off);
}
__device__ __forceinline__ const short* xaddrc(const short* base, int row, int col) {
    int off = ((row << 9) + (col << 1)) ^ xswz(row);
    return (const short*)((const char*)base + off);
}

// ---------------- weight prep: f32 row-major -> bf16 fragment-major (R7 verbatim) --
__global__ void prep_kernel(
    const float* __restrict__ W0, const float* __restrict__ W1, const float* __restrict__ W2,
    const float* __restrict__ W3, const float* __restrict__ W4, const float* __restrict__ W5,
    const float* __restrict__ W6, const float* __restrict__ W7, const float* __restrict__ W8,
    short* __restrict__ wbf)
{
    const int gid = blockIdx.x * blockDim.x + threadIdx.x;
    if (gid >= 68096) return;                       // total 16B chunks
    int l, cid; const float* Wsrc;
    if      (gid <  2048) { l = 0; cid = gid;         Wsrc = W0; }
    else if (gid < 10240) { l = 1; cid = gid -  2048; Wsrc = W1; }
    else if (gid < 18432) { l = 2; cid = gid - 10240; Wsrc = W2; }
    else if (gid < 26624) { l = 3; cid = gid - 18432; Wsrc = W3; }
    else if (gid < 34816) { l = 4; cid = gid - 26624; Wsrc = W4; }
    else if (gid < 43008) { l = 5; cid = gid - 34816; Wsrc = W5; }
    else if (gid < 51200) { l = 6; cid = gid - 43008; Wsrc = W6; }
    else if (gid < 59392) { l = 7; cid = gid - 51200; Wsrc = W7; }
    else                  { l = 8; cid = gid - 59392; Wsrc = W8; }
    const int NR   = (l == 3) ? 253 : ((l == 8) ? 257 : 256);
    const int KR   = (l == 0) ? 51 : 256;
    const int klog = (l == 0) ? 1 : 3;              // ktiles = Kpad/32 = 2 or 8
    const float sc = (l == 4) ? 0.70710678f : 1.0f; // fold skip 1/sqrt2 into W4
    const int lane  = cid & 63;
    const int tile  = cid >> 6;
    const int ntile = tile >> klog;
    const int ktile = tile & ((1 << klog) - 1);
    const int n  = ntile * 16 + (lane & 15);
    const int k0 = ktile * 32 + ((lane >> 4) << 3);
    bf16x8 v;
#pragma unroll
    for (int j = 0; j < 8; ++j) {
        int k = k0 + j;
        float f = (n < NR && k < KR) ? Wsrc[n * KR + k] * sc : 0.0f;
        v[j] = f2bf(f);
    }
    ((bf16x8*)wbf)[gid] = v;
}

// ------- one hidden layer, IN PLACE, a double-buffered, b single-buffered ----------
// ap in: ks=0 A-frags of THIS layer. ap out: ks=0 frags of NEXT layer (issued at
// the last K-step; ride through softplus + 2 barriers).
// MODE 0: normal. MODE 1: layer 3 (N=253: masked col block 252).
template<int KSTEPS, int MODE>
__device__ __forceinline__ void layer_fwd(short* xb,
    const bf16x8* __restrict__ wl, const bf16x8* __restrict__ wlnext,
    const float* __restrict__ bias, int lane, int wid, bf16x8 (&ap)[4])
{
    const int prow = lane & 15;
    const int kg   = (lane >> 4) << 3;
    const int rb4  = (lane >> 4) << 2;
    // bias folded into accumulator init (feature idx is mi-independent)
    f32x4 acc[4][4];
#pragma unroll
    for (int nii = 0; nii < 4; ++nii) {
        const int cb = (wid * 4 + nii) * 16 + rb4;
        f32x4 bv;
        if (MODE == 1 && cb == 252) { f32x4 tb = {bias[252], 0.f, 0.f, 0.f}; bv = tb; }
        else bv = *(const f32x4*)(bias + cb);
#pragma unroll
        for (int mi = 0; mi < 4; ++mi)
            acc[mi][nii] = bv;
    }
    bf16x8 a_cur[4];
#pragma unroll
    for (int nii = 0; nii < 4; ++nii) a_cur[nii] = ap[nii];
#pragma unroll
    for (int ks = 0; ks < KSTEPS; ++ks) {
        // a(ks+1) issues first: L2 latency hides under this ks's b-reads + MFMAs
        bf16x8 a_nxt[4];
        if (ks + 1 < KSTEPS) {
#pragma unroll
            for (int nii = 0; nii < 4; ++nii)
                a_nxt[nii] = wl[((wid * 4 + nii) * KSTEPS + ks + 1) * 64 + lane];
        } else {
#pragma unroll
            for (int nii = 0; nii < 4; ++nii)
                a_nxt[nii] = wlnext[(wid * 4 + nii) * 512 + lane];  // next layer ks=0
        }
        bf16x8 b[4];
#pragma unroll
        for (int mi = 0; mi < 4; ++mi)
            b[mi] = *(const bf16x8*)xaddrc(xb, mi * 16 + prow, ks * 32 + kg);
        __builtin_amdgcn_s_setprio(1);
#pragma unroll
        for (int mi = 0; mi < 4; ++mi)
#pragma unroll
            for (int nii = 0; nii < 4; ++nii)
                acc[mi][nii] = __builtin_amdgcn_mfma_f32_16x16x32_bf16(
                    a_cur[nii], b[mi], acc[mi][nii], 0, 0, 0);
        __builtin_amdgcn_s_setprio(0);
#pragma unroll
        for (int nii = 0; nii < 4; ++nii) a_cur[nii] = a_nxt[nii];
    }
#pragma unroll
    for (int nii = 0; nii < 4; ++nii) ap[nii] = a_cur[nii];
    // softplus in place on acc (registers only)
#pragma unroll
    for (int nii = 0; nii < 4; ++nii)
#pragma unroll
        for (int mi = 0; mi < 4; ++mi)
            sp100_4(acc[mi][nii]);
    bar_lgkm();                                       // all reads of xb complete
#pragma unroll
    for (int nii = 0; nii < 4; ++nii) {
        const int cb = (wid * 4 + nii) * 16 + rb4;
#pragma unroll
        for (int mi = 0; mi < 4; ++mi) {
            unsigned p01 = cvt_pk_bf16(acc[mi][nii][0], acc[mi][nii][1]);
            unsigned p23 = cvt_pk_bf16(acc[mi][nii][2], acc[mi][nii][3]);
            if (MODE == 1 && cb == 252) {
                *xaddr(xb, mi * 16 + prow, 252) = (short)(p01 & 0xffff);
            } else {
                uint2 pk; pk.x = p01; pk.y = p23;
                *(uint2*)xaddr(xb, mi * 16 + prow, cb) = pk;
            }
        }
    }
}

// ---------------- fused network kernel: 64 points, 4 waves, 32 KB LDS --------------
__global__ __launch_bounds__(256, 3) void net_kernel(
    const float* __restrict__ xin, const float* __restrict__ cond,
    const bf16x8* __restrict__ W,
    const float* __restrict__ b0, const float* __restrict__ b1, const float* __restrict__ b2,
    const float* __restrict__ b3, const float* __restrict__ b4, const float* __restrict__ b5,
    const float* __restrict__ b6, const float* __restrict__ b7, const float* __restrict__ b8,
    float* __restrict__ out)
{
    __shared__ short xb[64 * 256];
    const int t    = threadIdx.x;
    const int pt0  = blockIdx.x * 64;
    const int lane = t & 63;
    const int wid  = t >> 6;      // 0..3

    // prefetch L0 ks=0 A-frags first (hides cold weight fetch under X0 build)
    bf16x8 ap[4];
#pragma unroll
    for (int nii = 0; nii < 4; ++nii)
        ap[nii] = W[(wid * 4 + nii) * 128 + lane];   // KSTEPS(L0)=2

    // hoist skip values (written after layer 3; 1/sqrt2 folded into W4)
    float sk[3] = {0.f, 0.f, 0.f};
    if (t < 64) {
#pragma unroll
        for (int c = 0; c < 3; ++c)
            sk[c] = xin[(pt0 + t) * 3 + c];
    }

    // build X0 = [x(3) | cond(48) | zeros(..63)], bf16 into LDS cols 0..63
    {
        const int row   = t >> 2;           // 0..63
        const int c0    = (t & 3) << 4;     // 0,16,32,48
        const int point = pt0 + row;
        const int batch = point / PPTS;
        const float* xp = xin + point * 3;
        const float* cp = cond + batch * 48;
#pragma unroll
        for (int h = 0; h < 2; ++h) {
            bf16x8 v;
#pragma unroll
            for (int i = 0; i < 8; ++i) {
                int c = c0 + h * 8 + i;
                float f = (c < 3) ? xp[c] : ((c < 51) ? cp[c - 3] : 0.0f);
                v[i] = f2bf(f);
            }
            *(bf16x8*)xaddr(xb, row, c0 + h * 8) = v;
        }
    }
    bar_lgkm();

    layer_fwd<2, 0>(xb, W +     0, W +  2048, b0, lane, wid, ap); bar_lgkm();
    layer_fwd<8, 0>(xb, W +  2048, W + 10240, b1, lane, wid, ap); bar_lgkm();
    layer_fwd<8, 0>(xb, W + 10240, W + 18432, b2, lane, wid, ap); bar_lgkm();
    layer_fwd<8, 1>(xb, W + 18432, W + 26624, b3, lane, wid, ap);
    if (t < 64) {       // skip-concat cols 253..255 (same write window as L3)
#pragma unroll
        for (int c = 0; c < 3; ++c)
            *xaddr(xb, t, 253 + c) = f2bf(sk[c]);
    }
    bar_lgkm();
    layer_fwd<8, 0>(xb, W + 26624, W + 34816, b4, lane, wid, ap); bar_lgkm();
    layer_fwd<8, 0>(xb, W + 34816, W + 43008, b5, lane, wid, ap); bar_lgkm();
    layer_fwd<8, 0>(xb, W + 43008, W + 51200, b6, lane, wid, ap); bar_lgkm();
    layer_fwd<8, 0>(xb, W + 51200, W + 59392, b7, lane, wid, ap); bar_lgkm();

    // layer 8: N=257 (17 n-tiles), no activation, bias in acc-init, f32 store.
    // Two m-halves (live acc small); ap feeds half 0 ks 0; a double-buffered.
    {
        const bf16x8* wl = W + 59392;
        const int prow = lane & 15;
        const int kg   = (lane >> 4) << 3;
        const int rb4  = (lane >> 4) << 2;
        const float blast = b8[256];
#pragma unroll
        for (int half = 0; half < 2; ++half) {
            f32x4 acc[2][4];
            f32x4 acc2[2];
#pragma unroll
            for (int nii = 0; nii < 4; ++nii) {
                const int cb = (wid * 4 + nii) * 16 + rb4;          // <= 252
                const f32x4 bv = *(const f32x4*)(b8 + cb);
#pragma unroll
                for (int m2 = 0; m2 < 2; ++m2)
                    acc[m2][nii] = bv;
            }
            {
                f32x4 bz = {(rb4 == 0) ? blast : 0.f, 0.f, 0.f, 0.f};
                acc2[0] = bz; acc2[1] = bz;
            }
            bf16x8 a_cur[4];
#pragma unroll
            for (int nii = 0; nii < 4; ++nii)
                a_cur[nii] = (half == 0) ? ap[nii]
                           : wl[((wid * 4 + nii) * 8) * 64 + lane];
#pragma unroll
            for (int ks = 0; ks < 8; ++ks) {
                bf16x8 a_nxt[4], a2;
                if (ks < 7) {
#pragma unroll
                    for (int nii = 0; nii < 4; ++nii)
                        a_nxt[nii] = wl[((wid * 4 + nii) * 8 + ks + 1) * 64 + lane];
                }
                if (wid == 0) a2 = wl[(128 + ks) * 64 + lane];
                bf16x8 b[2];
#pragma unroll
                for (int m2 = 0; m2 < 2; ++m2)
                    b[m2] = *(const bf16x8*)xaddrc(xb, (half * 2 + m2) * 16 + prow,
                                                   ks * 32 + kg);
                __builtin_amdgcn_s_setprio(1);
#pragma unroll
                for (int m2 = 0; m2 < 2; ++m2)
#pragma unroll
                    for (int nii = 0; nii < 4; ++nii)
                        acc[m2][nii] = __builtin_amdgcn_mfma_f32_16x16x32_bf16(
                            a_cur[nii], b[m2], acc[m2][nii], 0, 0, 0);
                if (wid == 0) {
#pragma unroll
                    for (int m2 = 0; m2 < 2; ++m2)
                        acc2[m2] = __builtin_amdgcn_mfma_f32_16x16x32_bf16(
                            a2, b[m2], acc2[m2], 0, 0, 0);
                }
                __builtin_amdgcn_s_setprio(0);
                if (ks < 7) {
#pragma unroll
                    for (int nii = 0; nii < 4; ++nii) a_cur[nii] = a_nxt[nii];
                }
            }
#pragma unroll
            for (int nii = 0; nii < 4; ++nii) {
                const int cb = (wid * 4 + nii) * 16 + rb4;          // <= 252
#pragma unroll
                for (int m2 = 0; m2 < 2; ++m2) {
                    const int rowoff = (pt0 + (half * 2 + m2) * 16 + prow) * 257 + cb;
#pragma unroll
                    for (int r = 0; r < 4; ++r)
                        out[rowoff + r] = acc[m2][nii][r];
                }
            }
            if (wid == 0 && rb4 == 0) {                              // lanes 0..15
#pragma unroll
                for (int m2 = 0; m2 < 2; ++m2)
                    out[(pt0 + (half * 2 + m2) * 16 + prow) * 257 + 256]
                        = acc2[m2][0];
            }
        }
    }
}

extern "C" void kernel_launch(void* const* d_in, const int* in_sizes, int n_in,
                              void* d_out, int out_size, void* d_ws, size_t ws_size,
                              hipStream_t stream)
{
    const float* xin  = (const float*)d_in[0];
    const float* cond = (const float*)d_in[1];
    const float* Wp[9]; const float* bp[9];
    for (int l = 0; l < 9; ++l) { Wp[l] = (const float*)d_in[2 + 2 * l]; bp[l] = (const float*)d_in[3 + 2 * l]; }
    short* wbf = (short*)d_ws;   // needs 1,089,536 B

    prep_kernel<<<dim3(266), dim3(256), 0, stream>>>(
        Wp[0], Wp[1], Wp[2], Wp[3], Wp[4], Wp[5], Wp[6], Wp[7], Wp[8], wbf);
    net_kernel<<<dim3(3125), dim3(256), 0, stream>>>(
        xin, cond, (const bf16x8*)wbf,
        bp[0], bp[1], bp[2], bp[3], bp[4], bp[5], bp[6], bp[7], bp[8],
        (float*)d_out);
}

// Round 12
// 305.983 us; speedup vs baseline: 1.5226x; 1.5226x over previous
//
#include <hip/hip_runtime.h>

// ImplicitNet fused MLP — R12: 32x32x16 MFMA (R8 layout, HW-verified) at R10's
// 4-wave/64-pt geometry + ping-pong LDS (ONE barrier per layer).
// 256 threads (4 waves); wave owns 64 feats (2 nt tiles) x 64 pts (2 mt tiles):
// acc[2][2] f32x16 = 64 regs. launch_bounds(256,2): cap 256, no spill
// (R8's failure was the 128-reg cap at (512,4); R11 proved (256,3) unreachable).
// Ping-pong: src->dst per layer; a wave writes its outputs immediately after
// softplus (no read-complete barrier); single bar_lgkm per layer boundary.
//
// d_ws: bf16 weights, fragment-major 32x32x16 (R8 prep verbatim):
// chunk(nt,ks,lane) = W[nt*32+(lane&31)][ks*16+(lane>>5)*8+j]. L8 col 256 via
// 16x16x32 tail chunks at 67584. W4 pre-scaled by 1/sqrt2. Padding: L0 K 51->64,
// L3 N 253->256, L8 N 257->272(tail). ws >= 68096*16 = 1,089,536 B.

typedef __attribute__((ext_vector_type(8)))  short bf16x8;
typedef __attribute__((ext_vector_type(16))) float f32x16;
typedef __attribute__((ext_vector_type(4)))  float f32x4;
typedef __attribute__((ext_vector_type(2)))  float f32x2;

#define PPTS 50000

__device__ __forceinline__ short f2bf(float f) {
    union { float f; unsigned u; } v; v.f = f;
    unsigned r = v.u + 0x7fffu + ((v.u >> 16) & 1u);   // RTNE (finite inputs)
    return (short)(r >> 16);
}

__device__ __forceinline__ unsigned cvt_pk_bf16(float lo, float hi) {
    unsigned r;
    asm("v_cvt_pk_bf16_f32 %0, %1, %2" : "=v"(r) : "v"(lo), "v"(hi));
    return r;
}

// lgkm-only barrier: LDS ordering without draining the global (weight) queue.
__device__ __forceinline__ void bar_lgkm() {
    asm volatile("s_waitcnt lgkmcnt(0)" ::: "memory");
    __builtin_amdgcn_s_barrier();
    __builtin_amdgcn_sched_barrier(0);
}

// softplus(100x)/100 = max(x,0) + e*(A+Be+Ce^2), e=exp(-100|x|); |err|<=2.5e-5
__device__ __forceinline__ f32x2 sp100_pair(f32x2 y) {
    const f32x2 A2 = {6.9314718e-3f, 6.9314718e-3f};
    const f32x2 B2 = {-3.11522e-3f, -3.11522e-3f};
    const f32x2 C2 = {9.8829e-4f,  9.8829e-4f};
    const f32x2 K2 = {-144.26950408889634f, -144.26950408889634f};
    const f32x2 Z2 = {0.0f, 0.0f};
    f32x2 m = __builtin_elementwise_abs(y) * K2;
    f32x2 e = {__builtin_amdgcn_exp2f(m.x), __builtin_amdgcn_exp2f(m.y)};
    f32x2 t = __builtin_elementwise_fma(C2, e, B2);
    t = __builtin_elementwise_fma(t, e, A2);
    return __builtin_elementwise_fma(e, t, __builtin_elementwise_max(y, Z2));
}
__device__ __forceinline__ void sp100_16(f32x16& v) {
#pragma unroll
    for (int h = 0; h < 8; ++h) {
        f32x2 y = {v[2*h], v[2*h+1]};
        f32x2 r = sp100_pair(y);
        v[2*h] = r.x; v[2*h+1] = r.y;
    }
}

// LDS tile [64 rows][256 cols] bf16, row stride 512B.
// byte ^= ((row&7) ^ 5*bit3(row)) << 4 — bijective, keeps 8/16B alignment.
__device__ __forceinline__ int xswz(int row) {
    return (((row & 7) ^ (5 * ((row >> 3) & 1))) << 4);
}
__device__ __forceinline__ short* xaddr(short* base, int row, int col) {
    int off = ((row << 9) + (col << 1)) ^ xswz(row);
    return (short*)((char*)base + off);
}
__device__ __forceinline__ const short* xaddrc(const short* base, int row, int col) {
    int off = ((row << 9) + (col << 1)) ^ xswz(row);
    return (const short*)((const char*)base + off);
}

// ---------------- weight prep (R8 verbatim): f32 row-major -> bf16 frag-major ------
// Chunk offsets (16B units): L0:0(2048) L1:2048 L2:10240 L3:18432 L4:26624
// L5:34816 L6:43008 L7:51200 L8:59392(8192) tail:67584(512). Total 68096.
__global__ void prep_kernel(
    const float* __restrict__ W0, const float* __restrict__ W1, const float* __restrict__ W2,
    const float* __restrict__ W3, const float* __restrict__ W4, const float* __restrict__ W5,
    const float* __restrict__ W6, const float* __restrict__ W7, const float* __restrict__ W8,
    short* __restrict__ wbf)
{
    const int gid = blockIdx.x * blockDim.x + threadIdx.x;
    if (gid >= 68096) return;
    int l, cid; const float* Wsrc;
    if      (gid <  2048) { l = 0; cid = gid;         Wsrc = W0; }
    else if (gid < 10240) { l = 1; cid = gid -  2048; Wsrc = W1; }
    else if (gid < 18432) { l = 2; cid = gid - 10240; Wsrc = W2; }
    else if (gid < 26624) { l = 3; cid = gid - 18432; Wsrc = W3; }
    else if (gid < 34816) { l = 4; cid = gid - 26624; Wsrc = W4; }
    else if (gid < 43008) { l = 5; cid = gid - 34816; Wsrc = W5; }
    else if (gid < 51200) { l = 6; cid = gid - 43008; Wsrc = W6; }
    else if (gid < 59392) { l = 7; cid = gid - 51200; Wsrc = W7; }
    else if (gid < 67584) { l = 8; cid = gid - 59392; Wsrc = W8; }
    else                  { l = 9; cid = gid - 67584; Wsrc = W8; }   // tail
    const int lane = cid & 63;
    bf16x8 v;
    if (l <= 8) {   // 32x32x16 fragment layout
        const int NR   = (l == 3) ? 253 : ((l == 8) ? 257 : 256);
        const int KR   = (l == 0) ? 51 : 256;
        const int klog = (l == 0) ? 2 : 4;          // ks tiles: 4 or 16
        const float sc = (l == 4) ? 0.70710678f : 1.0f;
        const int tile = cid >> 6;
        const int nt   = tile >> klog;
        const int ks   = tile & ((1 << klog) - 1);
        const int n  = nt * 32 + (lane & 31);
        const int k0 = ks * 16 + ((lane >> 5) << 3);
#pragma unroll
        for (int j = 0; j < 8; ++j) {
            int k = k0 + j;
            float f = (n < NR && k < KR) ? Wsrc[n * KR + k] * sc : 0.0f;
            v[j] = f2bf(f);
        }
    } else {        // 16x16x32 tail fragments for L8 col 256
        const int ks = cid >> 6;
        const int n  = 256 + (lane & 15);
        const int k0 = ks * 32 + ((lane >> 4) << 3);
#pragma unroll
        for (int j = 0; j < 8; ++j) {
            int k = k0 + j;
            float f = (n < 257) ? Wsrc[n * 256 + k] : 0.0f;
            v[j] = f2bf(f);
        }
    }
    ((bf16x8*)wbf)[gid] = v;
}

// ------- one hidden layer, PING-PONG, 32x32x16, bias-in-C-init --------------------
// ap in: pair-0 (k2=0,1 x nt) A-frags of THIS layer. ap out: pair-0 of NEXT layer
// (issued after the K-loop; rides through softplus + write + barrier).
// MODE 0: normal. MODE 1: layer 3 (N=253: masked col group at 252).
template<int KS, int MODE>
__device__ __forceinline__ void layer32(const short* src, short* dst,
    const bf16x8* __restrict__ wl, const bf16x8* __restrict__ wlnext,
    const float* __restrict__ bias, int lane, int wid, bf16x8 (&ap)[2][2])
{
    const int p31  = lane & 31;
    const int hi   = lane >> 5;
    const int kcol = hi << 3;
    f32x16 acc[2][2];
#pragma unroll
    for (int nt = 0; nt < 2; ++nt) {
        const int ntb = (wid * 2 + nt) * 32;
        f32x16 bv;
#pragma unroll
        for (int q = 0; q < 4; ++q) {
            const int cb = ntb + 8 * q + 4 * hi;
            f32x4 b4;
            if (MODE == 1 && cb == 252) { f32x4 tb = {bias[252], 0.f, 0.f, 0.f}; b4 = tb; }
            else b4 = *(const f32x4*)(bias + cb);
#pragma unroll
            for (int r = 0; r < 4; ++r) bv[4 * q + r] = b4[r];
        }
        acc[0][nt] = bv; acc[1][nt] = bv;
    }
    bf16x8 ac[2][2];
#pragma unroll
    for (int k2 = 0; k2 < 2; ++k2)
#pragma unroll
        for (int nt = 0; nt < 2; ++nt) ac[k2][nt] = ap[k2][nt];
#pragma unroll
    for (int p = 0; p < KS / 2; ++p) {
        bf16x8 an[2][2];
        if (p + 1 < KS / 2) {
#pragma unroll
            for (int k2 = 0; k2 < 2; ++k2)
#pragma unroll
                for (int nt = 0; nt < 2; ++nt)
                    an[k2][nt] = wl[(((wid * 2 + nt) * KS) + 2 * (p + 1) + k2) * 64 + lane];
        }
        bf16x8 b[2][2];
#pragma unroll
        for (int k2 = 0; k2 < 2; ++k2)
#pragma unroll
            for (int mt = 0; mt < 2; ++mt)
                b[k2][mt] = *(const bf16x8*)xaddrc(src, mt * 32 + p31,
                                                   (2 * p + k2) * 16 + kcol);
        __builtin_amdgcn_s_setprio(1);
#pragma unroll
        for (int k2 = 0; k2 < 2; ++k2)
#pragma unroll
            for (int mt = 0; mt < 2; ++mt)
#pragma unroll
                for (int nt = 0; nt < 2; ++nt)
                    acc[mt][nt] = __builtin_amdgcn_mfma_f32_32x32x16_bf16(
                        ac[k2][nt], b[k2][mt], acc[mt][nt], 0, 0, 0);
        __builtin_amdgcn_s_setprio(0);
        if (p + 1 < KS / 2) {
#pragma unroll
            for (int k2 = 0; k2 < 2; ++k2)
#pragma unroll
                for (int nt = 0; nt < 2; ++nt) ac[k2][nt] = an[k2][nt];
        }
    }
    // prefetch next layer's pair-0 (KS_next = 16): rides through epilogue + bar
#pragma unroll
    for (int k2 = 0; k2 < 2; ++k2)
#pragma unroll
        for (int nt = 0; nt < 2; ++nt)
            ap[k2][nt] = wlnext[(((wid * 2 + nt) * 16) + k2) * 64 + lane];
    // softplus in place; write straight to dst (ping-pong: no read barrier needed)
#pragma unroll
    for (int mt = 0; mt < 2; ++mt)
#pragma unroll
        for (int nt = 0; nt < 2; ++nt) sp100_16(acc[mt][nt]);
#pragma unroll
    for (int mt = 0; mt < 2; ++mt) {
        const int row = mt * 32 + p31;
#pragma unroll
        for (int nt = 0; nt < 2; ++nt) {
            const int ntb = (wid * 2 + nt) * 32;
#pragma unroll
            for (int q = 0; q < 4; ++q) {
                const int cb = ntb + 8 * q + 4 * hi;
                unsigned p01 = cvt_pk_bf16(acc[mt][nt][4 * q],     acc[mt][nt][4 * q + 1]);
                unsigned p23 = cvt_pk_bf16(acc[mt][nt][4 * q + 2], acc[mt][nt][4 * q + 3]);
                if (MODE == 1 && cb == 252) {
                    *xaddr(dst, row, 252) = (short)(p01 & 0xffff);
                } else {
                    uint2 pk; pk.x = p01; pk.y = p23;
                    *(uint2*)xaddr(dst, row, cb) = pk;
                }
            }
        }
    }
}

// ---------------- fused network kernel: 64 points, 4 waves, 64 KB LDS --------------
__global__ __launch_bounds__(256, 2) void net_kernel(
    const float* __restrict__ xin, const float* __restrict__ cond,
    const bf16x8* __restrict__ W,
    const float* __restrict__ b0, const float* __restrict__ b1, const float* __restrict__ b2,
    const float* __restrict__ b3, const float* __restrict__ b4, const float* __restrict__ b5,
    const float* __restrict__ b6, const float* __restrict__ b7, const float* __restrict__ b8,
    float* __restrict__ out)
{
    __shared__ short xb0[64 * 256];
    __shared__ short xb1[64 * 256];
    const int t    = threadIdx.x;
    const int pt0  = blockIdx.x * 64;
    const int lane = t & 63;
    const int wid  = t >> 6;      // 0..3

    // prefetch L0 pair-0 A-frags first (KS(L0)=4)
    bf16x8 ap[2][2];
#pragma unroll
    for (int k2 = 0; k2 < 2; ++k2)
#pragma unroll
        for (int nt = 0; nt < 2; ++nt)
            ap[k2][nt] = W[(((wid * 2 + nt) * 4) + k2) * 64 + lane];

    // hoist skip values (written after layer 3; 1/sqrt2 folded into W4)
    float sk[3] = {0.f, 0.f, 0.f};
    if (t < 64) {
#pragma unroll
        for (int c = 0; c < 3; ++c)
            sk[c] = xin[(pt0 + t) * 3 + c];
    }

    // build X0 = [x(3) | cond(48) | zeros(..63)], bf16 into xb0 cols 0..63
    {
        const int row   = t >> 2;           // 0..63
        const int c0    = (t & 3) << 4;     // 0,16,32,48
        const int point = pt0 + row;
        const int batch = point / PPTS;
        const float* xp = xin + point * 3;
        const float* cp = cond + batch * 48;
#pragma unroll
        for (int h = 0; h < 2; ++h) {
            bf16x8 v;
#pragma unroll
            for (int i = 0; i < 8; ++i) {
                int c = c0 + h * 8 + i;
                float f = (c < 3) ? xp[c] : ((c < 51) ? cp[c - 3] : 0.0f);
                v[i] = f2bf(f);
            }
            *(bf16x8*)xaddr(xb0, row, c0 + h * 8) = v;
        }
    }
    bar_lgkm();

    layer32< 4, 0>(xb0, xb1, W +     0, W +  2048, b0, lane, wid, ap); bar_lgkm();
    layer32<16, 0>(xb1, xb0, W +  2048, W + 10240, b1, lane, wid, ap); bar_lgkm();
    layer32<16, 0>(xb0, xb1, W + 10240, W + 18432, b2, lane, wid, ap); bar_lgkm();
    layer32<16, 1>(xb1, xb0, W + 18432, W + 26624, b3, lane, wid, ap);
    if (t < 64) {       // skip-concat cols 253..255 into L4's input (xb0)
#pragma unroll
        for (int c = 0; c < 3; ++c)
            *xaddr(xb0, t, 253 + c) = f2bf(sk[c]);
    }
    bar_lgkm();
    layer32<16, 0>(xb0, xb1, W + 26624, W + 34816, b4, lane, wid, ap); bar_lgkm();
    layer32<16, 0>(xb1, xb0, W + 34816, W + 43008, b5, lane, wid, ap); bar_lgkm();
    layer32<16, 0>(xb0, xb1, W + 43008, W + 51200, b6, lane, wid, ap); bar_lgkm();
    layer32<16, 0>(xb1, xb0, W + 51200, W + 59392, b7, lane, wid, ap); bar_lgkm();

    // ---- layer 8 main: reads xb0; 8 nt tiles (cols 0..255); f32 stores ----
    {
        const bf16x8* wl = W + 59392;
        const int p31  = lane & 31;
        const int hi   = lane >> 5;
        const int kcol = hi << 3;
        f32x16 acc[2][2];
#pragma unroll
        for (int nt = 0; nt < 2; ++nt) {
            const int ntb = (wid * 2 + nt) * 32;
            f32x16 bv;
#pragma unroll
            for (int q = 0; q < 4; ++q) {
                const f32x4 b4 = *(const f32x4*)(b8 + ntb + 8 * q + 4 * hi);
#pragma unroll
                for (int r = 0; r < 4; ++r) bv[4 * q + r] = b4[r];
            }
            acc[0][nt] = bv; acc[1][nt] = bv;
        }
        bf16x8 ac[2][2];
#pragma unroll
        for (int k2 = 0; k2 < 2; ++k2)
#pragma unroll
            for (int nt = 0; nt < 2; ++nt) ac[k2][nt] = ap[k2][nt];
#pragma unroll
        for (int p = 0; p < 8; ++p) {
            bf16x8 an[2][2];
            if (p < 7) {
#pragma unroll
                for (int k2 = 0; k2 < 2; ++k2)
#pragma unroll
                    for (int nt = 0; nt < 2; ++nt)
                        an[k2][nt] = wl[(((wid * 2 + nt) * 16) + 2 * (p + 1) + k2) * 64 + lane];
            }
            bf16x8 b[2][2];
#pragma unroll
            for (int k2 = 0; k2 < 2; ++k2)
#pragma unroll
                for (int mt = 0; mt < 2; ++mt)
                    b[k2][mt] = *(const bf16x8*)xaddrc(xb0, mt * 32 + p31,
                                                       (2 * p + k2) * 16 + kcol);
            __builtin_amdgcn_s_setprio(1);
#pragma unroll
            for (int k2 = 0; k2 < 2; ++k2)
#pragma unroll
                for (int mt = 0; mt < 2; ++mt)
#pragma unroll
                    for (int nt = 0; nt < 2; ++nt)
                        acc[mt][nt] = __builtin_amdgcn_mfma_f32_32x32x16_bf16(
                            ac[k2][nt], b[k2][mt], acc[mt][nt], 0, 0, 0);
            __builtin_amdgcn_s_setprio(0);
            if (p < 7) {
#pragma unroll
                for (int k2 = 0; k2 < 2; ++k2)
#pragma unroll
                    for (int nt = 0; nt < 2; ++nt) ac[k2][nt] = an[k2][nt];
            }
        }
#pragma unroll
        for (int mt = 0; mt < 2; ++mt) {
            const int pt = pt0 + mt * 32 + p31;
#pragma unroll
            for (int nt = 0; nt < 2; ++nt) {
                const int ntb = (wid * 2 + nt) * 32;
#pragma unroll
                for (int q = 0; q < 4; ++q) {
                    const int cb = ntb + 8 * q + 4 * hi;
#pragma unroll
                    for (int r = 0; r < 4; ++r)
                        out[pt * 257 + cb + r] = acc[mt][nt][4 * q + r];
                }
            }
        }
    }
    // ---- layer 8 tail: col 256 via 16x16x32 frags (wave 0 only, rows 0..63) ----
    if (wid == 0) {
        const bf16x8* wt = W + 67584;
        const int prow = lane & 15;
        const float blast = b8[256];
        f32x4 acc2[4];
#pragma unroll
        for (int mi = 0; mi < 4; ++mi) { f32x4 z = {blast, 0.f, 0.f, 0.f}; acc2[mi] = z; }
#pragma unroll
        for (int ks = 0; ks < 8; ++ks) {
            const bf16x8 a2 = wt[ks * 64 + lane];
#pragma unroll
            for (int mi = 0; mi < 4; ++mi) {
                const bf16x8 bb = *(const bf16x8*)xaddrc(xb0, mi * 16 + prow,
                                                         ks * 32 + ((lane >> 4) << 3));
                acc2[mi] = __builtin_amdgcn_mfma_f32_16x16x32_bf16(a2, bb, acc2[mi], 0, 0, 0);
            }
        }
        if ((lane >> 4) == 0) {
#pragma unroll
            for (int mi = 0; mi < 4; ++mi)
                out[(pt0 + mi * 16 + prow) * 257 + 256] = acc2[mi][0];
        }
    }
}

extern "C" void kernel_launch(void* const* d_in, const int* in_sizes, int n_in,
                              void* d_out, int out_size, void* d_ws, size_t ws_size,
                              hipStream_t stream)
{
    const float* xin  = (const float*)d_in[0];
    const float* cond = (const float*)d_in[1];
    const float* Wp[9]; const float* bp[9];
    for (int l = 0; l < 9; ++l) { Wp[l] = (const float*)d_in[2 + 2 * l]; bp[l] = (const float*)d_in[3 + 2 * l]; }
    short* wbf = (short*)d_ws;   // needs 68096*16 = 1,089,536 B

    prep_kernel<<<dim3(266), dim3(256), 0, stream>>>(
        Wp[0], Wp[1], Wp[2], Wp[3], Wp[4], Wp[5], Wp[6], Wp[7], Wp[8], wbf);
    net_kernel<<<dim3(3125), dim3(256), 0, stream>>>(
        xin, cond, (const bf16x8*)wbf,
        bp[0], bp[1], bp[2], bp[3], bp[4], bp[5], bp[6], bp[7], bp[8],
        (float*)d_out);
}